// Round 7
// baseline (216.226 us; speedup 1.0000x reference)
//
#include <hip/hip_runtime.h>

// CausalSelfAttention: B=2, T=2048, DIM=1024, H=16, HD=64
// Inputs fp32; d_out fp32 = [out (B*T*DIM)] ++ [entropy (B*T)].
// Internal: bf16 MFMA, fp32 accumulation. 4 launches.

typedef unsigned short u16;
typedef __attribute__((ext_vector_type(8))) __bf16 bf16x8;
typedef __attribute__((ext_vector_type(4))) float float4v;

#define BQ 2
#define TQ 2048
#define DIMQ 1024
#define HQ 16
#define HDQ 64

__device__ __forceinline__ float4v mfma16(bf16x8 a, bf16x8 b, float4v c) {
    return __builtin_amdgcn_mfma_f32_16x16x32_bf16(a, b, c, 0, 0, 0);
}

__device__ __forceinline__ u16 f2bf(float f) {
    unsigned x = __float_as_uint(f);
    return (u16)((x + 0x7FFFu + ((x >> 16) & 1u)) >> 16);
}

__device__ __forceinline__ uint4 cvt8(float4 a, float4 b) {
    union { uint4 v; u16 u[8]; } r;
    r.u[0] = f2bf(a.x); r.u[1] = f2bf(a.y); r.u[2] = f2bf(a.z); r.u[3] = f2bf(a.w);
    r.u[4] = f2bf(b.x); r.u[5] = f2bf(b.y); r.u[6] = f2bf(b.z); r.u[7] = f2bf(b.w);
    return r.v;
}

// async global->LDS, 16B/lane; LDS dest must be wave-uniform base + lane*16
__device__ __forceinline__ void async16(const u16* g, u16* l) {
    __builtin_amdgcn_global_load_lds(
        (const __attribute__((address_space(1))) void*)g,
        (__attribute__((address_space(3))) void*)l, 16, 0, 0);
}

// ---------------------------------------------------------------------------
// transpose tile helper: in[R][C] fp32 -> out[C][R] bf16, 64x64 tile (tx,ty)
// ---------------------------------------------------------------------------
__device__ __forceinline__ void tr_tile(
    const float* __restrict__ in, u16* __restrict__ out, int R, int C,
    int tx, int ty, int tid, float (*T)[68])
{
    const int k0 = ty * 64, n0 = tx * 64;
    {
        int r = tid >> 2, cc = (tid & 3) << 4;
        const float* src = in + (size_t)(k0 + r) * C + n0 + cc;
        float4 v0 = ((const float4*)src)[0];
        float4 v1 = ((const float4*)src)[1];
        float4 v2 = ((const float4*)src)[2];
        float4 v3 = ((const float4*)src)[3];
        *(float4*)&T[r][cc + 0]  = v0;
        *(float4*)&T[r][cc + 4]  = v1;
        *(float4*)&T[r][cc + 8]  = v2;
        *(float4*)&T[r][cc + 12] = v3;
    }
    __syncthreads();
    {
        int nr = tid >> 2, kc = (tid & 3) << 4;
        union { uint4 v; u16 u[8]; } o0, o1;
#pragma unroll
        for (int j = 0; j < 8; ++j) o0.u[j] = f2bf(T[kc + j][nr]);
#pragma unroll
        for (int j = 0; j < 8; ++j) o1.u[j] = f2bf(T[kc + 8 + j][nr]);
        u16* dst = out + (size_t)(n0 + nr) * R + k0 + kc;
        ((uint4*)dst)[0] = o0.v;
        *(uint4*)(dst + 8) = o1.v;
    }
}

// ---------------------------------------------------------------------------
// fused pre-pass: [0,2048) x->bf16 ; [2048,2816) Wqkv^T ; [2816,3072) Wproj^T
// ---------------------------------------------------------------------------
__global__ __launch_bounds__(256) void prep_kernel(
    const float* __restrict__ x, const float* __restrict__ Wq,
    const float* __restrict__ Wp,
    u16* __restrict__ xb, u16* __restrict__ Wt, u16* __restrict__ Wpt)
{
    __shared__ float T[64][68];
    const int bx = blockIdx.x, tid = threadIdx.x;
    if (bx < 2048) {
        int i = (bx * 256 + tid) * 8;
        float4 a = *(const float4*)(x + i);
        float4 b = *(const float4*)(x + i + 4);
        *(uint4*)(xb + i) = cvt8(a, b);
    } else if (bx < 2816) {
        int bb = bx - 2048;
        tr_tile(Wq, Wt, DIMQ, 3 * DIMQ, bb % 48, bb / 48, tid, T);
    } else {
        int bb = bx - 2816;
        tr_tile(Wp, Wpt, DIMQ, DIMQ, bb & 15, bb >> 4, tid, T);
    }
}

// standalone Wproj^T (tight-ws fallback; runs after qkv GEMM frees Wt)
__global__ __launch_bounds__(256) void tr_cvt(
    const float* __restrict__ in, u16* __restrict__ out, int R, int C)
{
    __shared__ float T[64][68];
    tr_tile(in, out, R, C, blockIdx.x, blockIdx.y, threadIdx.x, T);
}

// ---------------------------------------------------------------------------
// Double-buffered GEMM: A[M][K] bf16, Bt[N][K] bf16. Tile TILEM x 128, BK=32.
// MODE 0: scatter -> Q(x0.125)[B,H,T,HD], K[B,H,T,HD], V^T[B,H,HD,T]
// MODE 1: fp32 store to Of; blocks bn==0,bm<16 also do entropy head-average.
// ---------------------------------------------------------------------------
template <int TILEM, int MODE>
__global__ __launch_bounds__(256) void gemm_db(
    const u16* __restrict__ A, const u16* __restrict__ Bt,
    int M, int N, int K,
    u16* __restrict__ Qo, u16* __restrict__ Ko, u16* __restrict__ Vt,
    float* __restrict__ Of, const float* __restrict__ EntIn)
{
    constexpr int MT = TILEM / 32;
    constexpr int AR = TILEM / 64;
    __shared__ u16 As[2][TILEM * 32];
    __shared__ u16 Bs[2][128 * 32];

    const int tid = threadIdx.x;
    const int bm = blockIdx.y, bn = blockIdx.x;
    const int wave = tid >> 6, lane = tid & 63;
    const int quad = lane >> 4, c = lane & 15;
    const int wm = wave >> 1, wn = wave & 1;
    const int x3 = c & 3;

    const float4v z = {0.f, 0.f, 0.f, 0.f};
    float4v acc[MT][4];
#pragma unroll
    for (int mt = 0; mt < MT; ++mt)
#pragma unroll
        for (int tn = 0; tn < 4; ++tn) acc[mt][tn] = z;

    const int srow = tid >> 2;
    const int schunk8 = (((tid & 3) ^ (srow & 3)) << 3);
    const u16* ga = A  + (size_t)(bm * TILEM + srow) * K + schunk8;
    const u16* gb = Bt + (size_t)(bn * 128  + srow) * K + schunk8;

#pragma unroll
    for (int p = 0; p < AR; ++p)
        async16(ga + (size_t)(p * 64) * K, As[0] + p * 2048 + tid * 8);
#pragma unroll
    for (int p = 0; p < 2; ++p)
        async16(gb + (size_t)(p * 64) * K, Bs[0] + p * 2048 + tid * 8);

    const int niter = K >> 5;
    for (int it = 0; it < niter; ++it) {
        __syncthreads();
        if (it + 1 < niter) {
            const int nb = (it + 1) & 1;
            const int kc = (it + 1) * 32;
#pragma unroll
            for (int p = 0; p < AR; ++p)
                async16(ga + kc + (size_t)(p * 64) * K, As[nb] + p * 2048 + tid * 8);
#pragma unroll
            for (int p = 0; p < 2; ++p)
                async16(gb + kc + (size_t)(p * 64) * K, Bs[nb] + p * 2048 + tid * 8);
        }
        const u16* as = As[it & 1];
        const u16* bs = Bs[it & 1];

        bf16x8 af[MT], bfr[4];
#pragma unroll
        for (int mt = 0; mt < MT; ++mt)
            af[mt] = *(const bf16x8*)&as[(wm * (TILEM / 2) + mt * 16 + c) * 32 +
                                         ((quad ^ x3) << 3)];
#pragma unroll
        for (int tn = 0; tn < 4; ++tn)
            bfr[tn] = *(const bf16x8*)&bs[(wn * 64 + tn * 16 + c) * 32 +
                                          ((quad ^ x3) << 3)];
#pragma unroll
        for (int mt = 0; mt < MT; ++mt)
#pragma unroll
            for (int tn = 0; tn < 4; ++tn)
                acc[mt][tn] = mfma16(af[mt], bfr[tn], acc[mt][tn]);
    }

#pragma unroll
    for (int mt = 0; mt < MT; ++mt)
#pragma unroll
        for (int tn = 0; tn < 4; ++tn) {
            int gm0 = bm * TILEM + wm * (TILEM / 2) + mt * 16 + quad * 4;
            int gn  = bn * 128 + wn * 64 + tn * 16 + c;
            if (MODE == 0) {
                int s = gn >> 10, h = (gn >> 6) & 15, d = gn & 63;
                int b = gm0 >> 11, t0 = gm0 & 2047;
                size_t bh = (size_t)(b * HQ + h);
                if (s == 2) {
                    union { unsigned long long w; u16 u[4]; } pk;
#pragma unroll
                    for (int r = 0; r < 4; ++r) pk.u[r] = f2bf(acc[mt][tn][r]);
                    *(unsigned long long*)&Vt[(bh * HDQ + d) * TQ + t0] = pk.w;
                } else {
                    u16* dst = (s == 0) ? Qo : Ko;
                    float sc = (s == 0) ? 0.125f : 1.0f;
#pragma unroll
                    for (int r = 0; r < 4; ++r)
                        dst[(bh * TQ + t0 + r) * HDQ + d] = f2bf(acc[mt][tn][r] * sc);
                }
            } else {
#pragma unroll
                for (int r = 0; r < 4; ++r)
                    Of[(size_t)(gm0 + r) * N + gn] = acc[mt][tn][r];
            }
        }

    if (MODE == 1 && bn == 0 && bm < 16) {
        int i = bm * 256 + tid;
        int b = i >> 11, t = i & 2047;
        float s = 0.f;
#pragma unroll
        for (int h = 0; h < HQ; ++h) s += EntIn[((size_t)(b * HQ + h)) * TQ + t];
        Of[(size_t)BQ * TQ * DIMQ + i] = s * (1.0f / HQ);
    }
}

// ---------------------------------------------------------------------------
// Flash attention + entropy, v7:
//  - 512-thread blocks (8 waves), grid (16 pairs, 32 bh) = 2 blocks/CU,
//    16 waves/CU.  Wave group g = wave>>2 handles key tiles jt = g (mod 2);
//    fixed-MX softmax is linear in keys, so partial (O,l,t) merge via LDS.
//  - Operand swap: S^T = K * Q^T (same frag reads, swapped MFMA args) so
//    P-writes pack into b64; O^T = V^T * P^T so AO stores pack into dwordx2.
//  - LDS 48 KB: K pair 16K + V pair 16K + per-wave P 16K.
// ---------------------------------------------------------------------------
__global__ __launch_bounds__(512, 4) void attn_kernel(
    const u16* __restrict__ Q, const u16* __restrict__ K,
    const u16* __restrict__ Vt, u16* __restrict__ AO,
    float* __restrict__ Ent)
{
    const int qt1 = blockIdx.x;                 // 0..15 (block 0 = most staging)
    const int qt2 = 31 - qt1;                   // 31..16
    const int bh = blockIdx.y;
    const int tid = threadIdx.x;
    const int wave = tid >> 6;                  // 0..7
    const int g = wave >> 2;                    // key-parity group
    const int w4 = wave & 3;                    // q-subtile
    const int lane = tid & 63;
    const int quad = lane >> 4, c = lane & 15;
    const int x7 = c & 7;

    __shared__ u16 smem[24576];                 // 48 KB
    u16* Ks = smem;                             // [2 parity][64x64]
    u16* Vs = smem + 8192;                      // [2 parity][64x64]
    u16* Ps = smem + 16384;                     // [8 waves][16q x 64k]

    const u16* Qp = Q  + (size_t)bh * TQ * HDQ;
    const u16* Kp = K  + (size_t)bh * TQ * HDQ;
    const u16* Vp = Vt + (size_t)bh * HDQ * TQ;

    const int q0[2] = { qt1 * 64 + w4 * 16, qt2 * 64 + w4 * 16 };

    bf16x8 qf[2][2];
#pragma unroll
    for (int s = 0; s < 2; ++s) {
        const u16* qr = Qp + (size_t)(q0[s] + c) * HDQ;
        qf[s][0] = *(const bf16x8*)(qr + quad * 8);
        qf[s][1] = *(const bf16x8*)(qr + 32 + quad * 8);
    }

    const float4v z = {0.f, 0.f, 0.f, 0.f};
    float4v oacc[2][4];
#pragma unroll
    for (int s = 0; s < 2; ++s)
#pragma unroll
        for (int tn = 0; tn < 4; ++tn) oacc[s][tn] = z;
    float lp[2] = {0.f, 0.f}, tp[2] = {0.f, 0.f};
    const float MX = 12.0f;

    u16* psw = Ps + wave * 1024;
    const int ntile = qt2 + 1;
    const int npair = (ntile + 1) >> 1;

    // staging: 512 threads cover one 64x64 u16 tile per async16 call
    const int srow = tid >> 3;                  // 0..63
    const int sch = ((tid & 7) ^ (srow & 7)) << 3;
    const u16* ka = Kp + (size_t)srow * HDQ + sch;
    const u16* va = Vp + (size_t)srow * TQ + sch;

    for (int pr = 0; pr < npair; ++pr) {
        const int j0 = 2 * pr, j1 = 2 * pr + 1;
        __syncthreads();                        // previous pair fully consumed
        async16(ka + (size_t)(j0 * 64) * HDQ, Ks + tid * 8);
        async16(va + j0 * 64, Vs + tid * 8);
        if (j1 < ntile) {
            async16(ka + (size_t)(j1 * 64) * HDQ, Ks + 4096 + tid * 8);
            async16(va + j1 * 64, Vs + 4096 + tid * 8);
        }
        __syncthreads();                        // staged pair visible

        const int jt = 2 * pr + g;
        if (jt < ntile) {
            const u16* ksb = Ks + g * 4096;
            const u16* vsb = Vs + g * 4096;

            bf16x8 kf[4][2];
#pragma unroll
            for (int tn = 0; tn < 4; ++tn) {
                int base = (tn * 16 + c) * 64;
                kf[tn][0] = *(const bf16x8*)&ksb[base + ((quad ^ x7) << 3)];
                kf[tn][1] = *(const bf16x8*)&ksb[base + (((quad + 4) ^ x7) << 3)];
            }

#pragma unroll
            for (int s = 0; s < 2; ++s) {
                if (s == 0 && jt > qt1) continue;
                const int diag = s ? qt2 : qt1;
                // S^T per key-tile tn: rows=keys, cols=q. Immediate softmax.
#pragma unroll
                for (int tn = 0; tn < 4; ++tn) {
                    float4v sacc = z;
                    sacc = mfma16(kf[tn][0], qf[s][0], sacc);
                    sacc = mfma16(kf[tn][1], qf[s][1], sacc);
                    if (jt == diag) {
#pragma unroll
                        for (int r = 0; r < 4; ++r) {
                            int kg = jt * 64 + tn * 16 + quad * 4 + r;
                            if (kg > q0[s] + c) sacc[r] = -1e30f;
                        }
                    }
                    unsigned u[4];
#pragma unroll
                    for (int r = 0; r < 4; ++r) {
                        float sv = sacc[r];
                        float p = __expf(sv - MX);
                        lp[s] += p;
                        tp[s] += p * sv;
                        u[r] = __float_as_uint(p);
                    }
                    uint2 pk;
                    pk.x = (u[0] >> 16) | (u[1] & 0xffff0000u);
                    pk.y = (u[2] >> 16) | (u[3] & 0xffff0000u);
                    int kc8 = tn * 2 + (quad >> 1);
                    *(uint2*)&psw[c * 64 + ((kc8 ^ x7) << 3) + (quad & 1) * 4] = pk;
                }
                // O^T += V^T * P^T
                bf16x8 pf0 = *(const bf16x8*)&psw[c * 64 + ((quad ^ x7) << 3)];
                bf16x8 pf1 = *(const bf16x8*)&psw[c * 64 + (((quad + 4) ^ x7) << 3)];
#pragma unroll
                for (int tn = 0; tn < 4; ++tn) {
                    int base = (tn * 16 + c) * 64;
                    bf16x8 vf0 = *(const bf16x8*)&vsb[base + ((quad ^ x7) << 3)];
                    bf16x8 vf1 = *(const bf16x8*)&vsb[base + (((quad + 4) ^ x7) << 3)];
                    oacc[s][tn] = mfma16(vf0, pf0, oacc[s][tn]);
                    oacc[s][tn] = mfma16(vf1, pf1, oacc[s][tn]);
                }
            }
        }
    }

    // merge group 1 partials into group 0 via LDS
    __syncthreads();
    float* xfer = (float*)smem;                  // 32 KB (Ks+Vs region)
    float* xlt  = (float*)(smem + 16384);        // 4 KB  (Ps region)
    if (g == 1) {
#pragma unroll
        for (int s = 0; s < 2; ++s) {
#pragma unroll
            for (int tn = 0; tn < 4; ++tn)
                *(float4v*)&xfer[((((w4 * 2 + s) * 4 + tn) * 64) + lane) * 4] =
                    oacc[s][tn];
            xlt[((w4 * 2 + s) * 2 + 0) * 64 + lane] = lp[s];
            xlt[((w4 * 2 + s) * 2 + 1) * 64 + lane] = tp[s];
        }
    }
    __syncthreads();
    if (g == 0) {
#pragma unroll
        for (int s = 0; s < 2; ++s) {
#pragma unroll
            for (int tn = 0; tn < 4; ++tn)
                oacc[s][tn] += *(const float4v*)
                    &xfer[((((w4 * 2 + s) * 4 + tn) * 64) + lane) * 4];
            lp[s] += xlt[((w4 * 2 + s) * 2 + 0) * 64 + lane];
            tp[s] += xlt[((w4 * 2 + s) * 2 + 1) * 64 + lane];
            // reduce across quads (lanes c, c+16, c+32, c+48 share q=c)
            lp[s] += __shfl_xor(lp[s], 16); lp[s] += __shfl_xor(lp[s], 32);
            tp[s] += __shfl_xor(tp[s], 16); tp[s] += __shfl_xor(tp[s], 32);
        }
        const int b = bh >> 4, h = bh & 15;
#pragma unroll
        for (int s = 0; s < 2; ++s) {
            float inv = 1.0f / lp[s];
            u16* dst = AO + ((size_t)(b * TQ + q0[s] + c)) * DIMQ + h * HDQ;
#pragma unroll
            for (int tn = 0; tn < 4; ++tn) {
                unsigned u[4];
#pragma unroll
                for (int r = 0; r < 4; ++r)
                    u[r] = (unsigned)f2bf(oacc[s][tn][r] * inv);
                uint2 pk;
                pk.x = u[0] | (u[1] << 16);
                pk.y = u[2] | (u[3] << 16);
                *(uint2*)(dst + tn * 16 + quad * 4) = pk;
            }
            if (quad == 0)
                Ent[(size_t)bh * TQ + q0[s] + c] =
                    MX + logf(lp[s]) - tp[s] / lp[s];
        }
    }
}

extern "C" void kernel_launch(void* const* d_in, const int* in_sizes, int n_in,
                              void* d_out, int out_size, void* d_ws, size_t ws_size,
                              hipStream_t stream) {
    const float* x     = (const float*)d_in[0];
    const float* Wqkv  = (const float*)d_in[1];
    const float* Wproj = (const float*)d_in[2];
    float* out = (float*)d_out;

    const size_t NE = (size_t)BQ * HQ * TQ * HDQ;   // 4,194,304
    const size_t WQN = (size_t)3 * DIMQ * DIMQ;
    const size_t WPN = (size_t)DIMQ * DIMQ;
    u16* Qb  = (u16*)d_ws;
    u16* Kb  = Qb + NE;
    u16* Vtb = Kb + NE;
    u16* xb  = Vtb + NE;
    u16* Wt  = xb + NE;
    u16* AO  = xb;

    const size_t need = (4 * NE + WQN + WPN) * 2 + (size_t)BQ * HQ * TQ * 4;
    const bool room = ws_size >= need;
    u16* Wpt = room ? (Wt + WQN) : Wt;
    float* Ent = room ? (float*)(Wpt + WPN) : (float*)(Wt + WQN);

    prep_kernel<<<dim3(room ? 3072 : 2816), 256, 0, stream>>>(
        x, Wqkv, Wproj, xb, Wt, Wpt);
    gemm_db<128, 0><<<dim3(24, 32), 256, 0, stream>>>(
        xb, Wt, BQ * TQ, 3 * DIMQ, DIMQ, Qb, Kb, Vtb, nullptr, nullptr);
    if (!room)
        tr_cvt<<<dim3(16, 16), 256, 0, stream>>>(Wproj, Wpt, DIMQ, DIMQ);
    attn_kernel<<<dim3(16, BQ * HQ), 512, 0, stream>>>(Qb, Kb, Vtb, AO, Ent);
    gemm_db<64, 1><<<dim3(8, 64), 256, 0, stream>>>(
        AO, Wpt, BQ * TQ, DIMQ, DIMQ, nullptr, nullptr, nullptr, out, Ent);
}

// Round 8
// 177.147 us; speedup vs baseline: 1.2206x; 1.2206x over previous
//
#include <hip/hip_runtime.h>

// CausalSelfAttention: B=2, T=2048, DIM=1024, H=16, HD=64
// Inputs fp32; d_out fp32 = [out (B*T*DIM)] ++ [entropy (B*T)].
// Internal: bf16 MFMA, fp32 accumulation. 4 launches.

typedef unsigned short u16;
typedef __attribute__((ext_vector_type(8))) __bf16 bf16x8;
typedef __attribute__((ext_vector_type(4))) float float4v;

#define BQ 2
#define TQ 2048
#define DIMQ 1024
#define HQ 16
#define HDQ 64

__device__ __forceinline__ float4v mfma16(bf16x8 a, bf16x8 b, float4v c) {
    return __builtin_amdgcn_mfma_f32_16x16x32_bf16(a, b, c, 0, 0, 0);
}

__device__ __forceinline__ u16 f2bf(float f) {
    unsigned x = __float_as_uint(f);
    return (u16)((x + 0x7FFFu + ((x >> 16) & 1u)) >> 16);
}

__device__ __forceinline__ uint4 cvt8(float4 a, float4 b) {
    union { uint4 v; u16 u[8]; } r;
    r.u[0] = f2bf(a.x); r.u[1] = f2bf(a.y); r.u[2] = f2bf(a.z); r.u[3] = f2bf(a.w);
    r.u[4] = f2bf(b.x); r.u[5] = f2bf(b.y); r.u[6] = f2bf(b.z); r.u[7] = f2bf(b.w);
    return r.v;
}

// async global->LDS, 16B/lane; LDS dest must be wave-uniform base + lane*16
__device__ __forceinline__ void async16(const u16* g, u16* l) {
    __builtin_amdgcn_global_load_lds(
        (const __attribute__((address_space(1))) void*)g,
        (__attribute__((address_space(3))) void*)l, 16, 0, 0);
}

// ---------------------------------------------------------------------------
// transpose tile helper: in[R][C] fp32 -> out[C][R] bf16, 64x64 tile (tx,ty)
// ---------------------------------------------------------------------------
__device__ __forceinline__ void tr_tile(
    const float* __restrict__ in, u16* __restrict__ out, int R, int C,
    int tx, int ty, int tid, float (*T)[68])
{
    const int k0 = ty * 64, n0 = tx * 64;
    {
        int r = tid >> 2, cc = (tid & 3) << 4;
        const float* src = in + (size_t)(k0 + r) * C + n0 + cc;
        float4 v0 = ((const float4*)src)[0];
        float4 v1 = ((const float4*)src)[1];
        float4 v2 = ((const float4*)src)[2];
        float4 v3 = ((const float4*)src)[3];
        *(float4*)&T[r][cc + 0]  = v0;
        *(float4*)&T[r][cc + 4]  = v1;
        *(float4*)&T[r][cc + 8]  = v2;
        *(float4*)&T[r][cc + 12] = v3;
    }
    __syncthreads();
    {
        int nr = tid >> 2, kc = (tid & 3) << 4;
        union { uint4 v; u16 u[8]; } o0, o1;
#pragma unroll
        for (int j = 0; j < 8; ++j) o0.u[j] = f2bf(T[kc + j][nr]);
#pragma unroll
        for (int j = 0; j < 8; ++j) o1.u[j] = f2bf(T[kc + 8 + j][nr]);
        u16* dst = out + (size_t)(n0 + nr) * R + k0 + kc;
        ((uint4*)dst)[0] = o0.v;
        *(uint4*)(dst + 8) = o1.v;
    }
}

// ---------------------------------------------------------------------------
// fused pre-pass: [0,2048) x->bf16 ; [2048,2816) Wqkv^T ; [2816,3072) Wproj^T
// ---------------------------------------------------------------------------
__global__ __launch_bounds__(256) void prep_kernel(
    const float* __restrict__ x, const float* __restrict__ Wq,
    const float* __restrict__ Wp,
    u16* __restrict__ xb, u16* __restrict__ Wt, u16* __restrict__ Wpt)
{
    __shared__ float T[64][68];
    const int bx = blockIdx.x, tid = threadIdx.x;
    if (bx < 2048) {
        int i = (bx * 256 + tid) * 8;
        float4 a = *(const float4*)(x + i);
        float4 b = *(const float4*)(x + i + 4);
        *(uint4*)(xb + i) = cvt8(a, b);
    } else if (bx < 2816) {
        int bb = bx - 2048;
        tr_tile(Wq, Wt, DIMQ, 3 * DIMQ, bb % 48, bb / 48, tid, T);
    } else {
        int bb = bx - 2816;
        tr_tile(Wp, Wpt, DIMQ, DIMQ, bb & 15, bb >> 4, tid, T);
    }
}

// standalone Wproj^T (tight-ws fallback; runs after qkv GEMM frees Wt)
__global__ __launch_bounds__(256) void tr_cvt(
    const float* __restrict__ in, u16* __restrict__ out, int R, int C)
{
    __shared__ float T[64][68];
    tr_tile(in, out, R, C, blockIdx.x, blockIdx.y, threadIdx.x, T);
}

// ---------------------------------------------------------------------------
// Double-buffered GEMM: A[M][K] bf16, Bt[N][K] bf16. Tile TILEM x 128, BK=32.
// MODE 0: scatter -> Q(x0.125)[B,H,T,HD], K[B,H,T,HD], V^T[B,H,HD,T]
// MODE 1: fp32 store to Of; blocks bn==0,bm<16 also do entropy head-average.
// ---------------------------------------------------------------------------
template <int TILEM, int MODE>
__global__ __launch_bounds__(256) void gemm_db(
    const u16* __restrict__ A, const u16* __restrict__ Bt,
    int M, int N, int K,
    u16* __restrict__ Qo, u16* __restrict__ Ko, u16* __restrict__ Vt,
    float* __restrict__ Of, const float* __restrict__ EntIn)
{
    constexpr int MT = TILEM / 32;
    constexpr int AR = TILEM / 64;
    __shared__ u16 As[2][TILEM * 32];
    __shared__ u16 Bs[2][128 * 32];

    const int tid = threadIdx.x;
    const int bm = blockIdx.y, bn = blockIdx.x;
    const int wave = tid >> 6, lane = tid & 63;
    const int quad = lane >> 4, c = lane & 15;
    const int wm = wave >> 1, wn = wave & 1;
    const int x3 = c & 3;

    const float4v z = {0.f, 0.f, 0.f, 0.f};
    float4v acc[MT][4];
#pragma unroll
    for (int mt = 0; mt < MT; ++mt)
#pragma unroll
        for (int tn = 0; tn < 4; ++tn) acc[mt][tn] = z;

    const int srow = tid >> 2;
    const int schunk8 = (((tid & 3) ^ (srow & 3)) << 3);
    const u16* ga = A  + (size_t)(bm * TILEM + srow) * K + schunk8;
    const u16* gb = Bt + (size_t)(bn * 128  + srow) * K + schunk8;

#pragma unroll
    for (int p = 0; p < AR; ++p)
        async16(ga + (size_t)(p * 64) * K, As[0] + p * 2048 + tid * 8);
#pragma unroll
    for (int p = 0; p < 2; ++p)
        async16(gb + (size_t)(p * 64) * K, Bs[0] + p * 2048 + tid * 8);

    const int niter = K >> 5;
    for (int it = 0; it < niter; ++it) {
        __syncthreads();
        if (it + 1 < niter) {
            const int nb = (it + 1) & 1;
            const int kc = (it + 1) * 32;
#pragma unroll
            for (int p = 0; p < AR; ++p)
                async16(ga + kc + (size_t)(p * 64) * K, As[nb] + p * 2048 + tid * 8);
#pragma unroll
            for (int p = 0; p < 2; ++p)
                async16(gb + kc + (size_t)(p * 64) * K, Bs[nb] + p * 2048 + tid * 8);
        }
        const u16* as = As[it & 1];
        const u16* bs = Bs[it & 1];

        bf16x8 af[MT], bfr[4];
#pragma unroll
        for (int mt = 0; mt < MT; ++mt)
            af[mt] = *(const bf16x8*)&as[(wm * (TILEM / 2) + mt * 16 + c) * 32 +
                                         ((quad ^ x3) << 3)];
#pragma unroll
        for (int tn = 0; tn < 4; ++tn)
            bfr[tn] = *(const bf16x8*)&bs[(wn * 64 + tn * 16 + c) * 32 +
                                          ((quad ^ x3) << 3)];
#pragma unroll
        for (int mt = 0; mt < MT; ++mt)
#pragma unroll
            for (int tn = 0; tn < 4; ++tn)
                acc[mt][tn] = mfma16(af[mt], bfr[tn], acc[mt][tn]);
    }

#pragma unroll
    for (int mt = 0; mt < MT; ++mt)
#pragma unroll
        for (int tn = 0; tn < 4; ++tn) {
            int gm0 = bm * TILEM + wm * (TILEM / 2) + mt * 16 + quad * 4;
            int gn  = bn * 128 + wn * 64 + tn * 16 + c;
            if (MODE == 0) {
                int s = gn >> 10, h = (gn >> 6) & 15, d = gn & 63;
                int b = gm0 >> 11, t0 = gm0 & 2047;
                size_t bh = (size_t)(b * HQ + h);
                if (s == 2) {
                    union { unsigned long long w; u16 u[4]; } pk;
#pragma unroll
                    for (int r = 0; r < 4; ++r) pk.u[r] = f2bf(acc[mt][tn][r]);
                    *(unsigned long long*)&Vt[(bh * HDQ + d) * TQ + t0] = pk.w;
                } else {
                    u16* dst = (s == 0) ? Qo : Ko;
                    float sc = (s == 0) ? 0.125f : 1.0f;
#pragma unroll
                    for (int r = 0; r < 4; ++r)
                        dst[(bh * TQ + t0 + r) * HDQ + d] = f2bf(acc[mt][tn][r] * sc);
                }
            } else {
#pragma unroll
                for (int r = 0; r < 4; ++r)
                    Of[(size_t)(gm0 + r) * N + gn] = acc[mt][tn][r];
            }
        }

    if (MODE == 1 && bn == 0 && bm < 16) {
        int i = bm * 256 + tid;
        int b = i >> 11, t = i & 2047;
        float s = 0.f;
#pragma unroll
        for (int h = 0; h < HQ; ++h) s += EntIn[((size_t)(b * HQ + h)) * TQ + t];
        Of[(size_t)BQ * TQ * DIMQ + i] = s * (1.0f / HQ);
    }
}

// ---------------------------------------------------------------------------
// Flash attention + entropy, v8 = round-6 structure + HW-validated operand
// swap (round 7, bit-identical absmax):
//  - 256-thread blocks, paired causal q-tiles (qt1=bx, qt2=31-bx), dbuf K/V.
//  - S^T = K * Q^T: C-layout rows = keys, cols = q -> P writes pack into b64,
//    lp/tp become per-lane scalars (q = lane&15).
//  - O^T = V^T * P^T: epilogue packs into uint2 stores.
// ---------------------------------------------------------------------------
__global__ __launch_bounds__(256) void attn_kernel(
    const u16* __restrict__ Q, const u16* __restrict__ K,
    const u16* __restrict__ Vt, u16* __restrict__ AO,
    float* __restrict__ Ent)
{
    const int qt1 = blockIdx.x;                 // 0..15 (block 0 = most staging)
    const int qt2 = 31 - qt1;                   // 31..16
    const int bh = blockIdx.y;
    const int tid = threadIdx.x;
    const int wave = tid >> 6, lane = tid & 63;
    const int quad = lane >> 4, c = lane & 15;
    const int x7 = c & 7;

    __shared__ u16 Ks[2][64 * 64];   // dbuf K tiles [key][d], chunk-swizzled
    __shared__ u16 Vs[2][64 * 64];   // dbuf V^T tiles [d][key], chunk-swizzled
    __shared__ u16 Ps[4][16 * 64];   // per-wave P^T-source [q][key], swizzled

    const u16* Qp = Q  + (size_t)bh * TQ * HDQ;
    const u16* Kp = K  + (size_t)bh * TQ * HDQ;
    const u16* Vp = Vt + (size_t)bh * HDQ * TQ;

    const int q0[2] = { qt1 * 64 + wave * 16, qt2 * 64 + wave * 16 };

    // Q^T B-fragments: lane n=c -> q=q0[s]+c, k-chunks quad, quad+4
    bf16x8 qf[2][2];
#pragma unroll
    for (int s = 0; s < 2; ++s) {
        const u16* qr = Qp + (size_t)(q0[s] + c) * HDQ;
        qf[s][0] = *(const bf16x8*)(qr + quad * 8);
        qf[s][1] = *(const bf16x8*)(qr + 32 + quad * 8);
    }

    const float4v z = {0.f, 0.f, 0.f, 0.f};
    float4v oacc[2][4];
#pragma unroll
    for (int s = 0; s < 2; ++s)
#pragma unroll
        for (int tn = 0; tn < 4; ++tn) oacc[s][tn] = z;
    float lp[2] = {0.f, 0.f}, tp[2] = {0.f, 0.f};
    const float MX = 12.0f;

    u16* psw = &Ps[wave][0];
    const int ntile = qt2 + 1;

    const int srow = tid >> 3;
    const int schunk8 = (((tid & 7) ^ (srow & 7)) << 3);
    const u16* ka = Kp + (size_t)srow * HDQ + schunk8;
    const u16* va = Vp + (size_t)srow * TQ + schunk8;

    {
        async16(ka, Ks[0] + tid * 8);
        async16(ka + (size_t)32 * HDQ, Ks[0] + 2048 + tid * 8);
        async16(va, Vs[0] + tid * 8);
        async16(va + (size_t)32 * TQ, Vs[0] + 2048 + tid * 8);
    }

    for (int jt = 0; jt < ntile; ++jt) {
        __syncthreads();
        if (jt + 1 < ntile) {
            int nb = (jt + 1) & 1;
            async16(ka + (size_t)((jt + 1) * 64) * HDQ, Ks[nb] + tid * 8);
            async16(ka + (size_t)((jt + 1) * 64 + 32) * HDQ, Ks[nb] + 2048 + tid * 8);
            async16(va + (jt + 1) * 64, Vs[nb] + tid * 8);
            async16(va + (size_t)32 * TQ + (jt + 1) * 64, Vs[nb] + 2048 + tid * 8);
        }
        const u16* ksb = Ks[jt & 1];
        const u16* vsb = Vs[jt & 1];

        // K (A-operand) and V^T (A-operand) fragments, rows tn*16+c
        bf16x8 kf[4][2], vf[4][2];
#pragma unroll
        for (int tn = 0; tn < 4; ++tn) {
            int base = (tn * 16 + c) * 64;
            kf[tn][0] = *(const bf16x8*)&ksb[base + ((quad ^ x7) << 3)];
            kf[tn][1] = *(const bf16x8*)&ksb[base + (((quad + 4) ^ x7) << 3)];
            vf[tn][0] = *(const bf16x8*)&vsb[base + ((quad ^ x7) << 3)];
            vf[tn][1] = *(const bf16x8*)&vsb[base + (((quad + 4) ^ x7) << 3)];
        }

#pragma unroll
        for (int s = 0; s < 2; ++s) {
            if (s == 0 && jt > qt1) continue;
            const int diag = s ? qt2 : qt1;
            // S^T per key-subtile tn: C rows = keys, cols = q
#pragma unroll
            for (int tn = 0; tn < 4; ++tn) {
                float4v sacc = z;
                sacc = mfma16(kf[tn][0], qf[s][0], sacc);
                sacc = mfma16(kf[tn][1], qf[s][1], sacc);
                if (jt == diag) {
#pragma unroll
                    for (int r = 0; r < 4; ++r) {
                        int kg = jt * 64 + tn * 16 + quad * 4 + r;
                        if (kg > q0[s] + c) sacc[r] = -1e30f;
                    }
                }
                unsigned u[4];
#pragma unroll
                for (int r = 0; r < 4; ++r) {
                    float sv = sacc[r];
                    float p = __expf(sv - MX);
                    lp[s] += p;
                    tp[s] += p * sv;
                    u[r] = __float_as_uint(p);
                }
                uint2 pk;
                pk.x = (u[0] >> 16) | (u[1] & 0xffff0000u);
                pk.y = (u[2] >> 16) | (u[3] & 0xffff0000u);
                int kc8 = tn * 2 + (quad >> 1);   // key/8 chunk
                *(uint2*)&psw[c * 64 + ((kc8 ^ x7) << 3) + (quad & 1) * 4] = pk;
            }
            // P^T B-fragments (row q=c, 8-key chunks quad, quad+4)
            bf16x8 pf0 = *(const bf16x8*)&psw[c * 64 + ((quad ^ x7) << 3)];
            bf16x8 pf1 = *(const bf16x8*)&psw[c * 64 + (((quad + 4) ^ x7) << 3)];
            // O^T += V^T * P^T  (C rows = d, cols = q)
#pragma unroll
            for (int tn = 0; tn < 4; ++tn) {
                oacc[s][tn] = mfma16(vf[tn][0], pf0, oacc[s][tn]);
                oacc[s][tn] = mfma16(vf[tn][1], pf1, oacc[s][tn]);
            }
        }
    }

    // reduce l/t across quads (lanes c, c+16, c+32, c+48 share q=c)
#pragma unroll
    for (int s = 0; s < 2; ++s) {
        lp[s] += __shfl_xor(lp[s], 16); lp[s] += __shfl_xor(lp[s], 32);
        tp[s] += __shfl_xor(tp[s], 16); tp[s] += __shfl_xor(tp[s], 32);
    }

    const int b = bh >> 4, h = bh & 15;
#pragma unroll
    for (int s = 0; s < 2; ++s) {
        float inv = 1.0f / lp[s];
        u16* dst = AO + ((size_t)(b * TQ + q0[s] + c)) * DIMQ + h * HDQ;
#pragma unroll
        for (int tn = 0; tn < 4; ++tn) {
            unsigned u[4];
#pragma unroll
            for (int r = 0; r < 4; ++r)
                u[r] = (unsigned)f2bf(oacc[s][tn][r] * inv);
            uint2 pk;
            pk.x = u[0] | (u[1] << 16);
            pk.y = u[2] | (u[3] << 16);
            *(uint2*)(dst + tn * 16 + quad * 4) = pk;
        }
        if (quad == 0)
            Ent[(size_t)bh * TQ + q0[s] + c] =
                MX + logf(lp[s]) - tp[s] / lp[s];
    }
}

extern "C" void kernel_launch(void* const* d_in, const int* in_sizes, int n_in,
                              void* d_out, int out_size, void* d_ws, size_t ws_size,
                              hipStream_t stream) {
    const float* x     = (const float*)d_in[0];
    const float* Wqkv  = (const float*)d_in[1];
    const float* Wproj = (const float*)d_in[2];
    float* out = (float*)d_out;

    const size_t NE = (size_t)BQ * HQ * TQ * HDQ;   // 4,194,304
    const size_t WQN = (size_t)3 * DIMQ * DIMQ;
    const size_t WPN = (size_t)DIMQ * DIMQ;
    u16* Qb  = (u16*)d_ws;
    u16* Kb  = Qb + NE;
    u16* Vtb = Kb + NE;
    u16* xb  = Vtb + NE;
    u16* Wt  = xb + NE;
    u16* AO  = xb;

    const size_t need = (4 * NE + WQN + WPN) * 2 + (size_t)BQ * HQ * TQ * 4;
    const bool room = ws_size >= need;
    u16* Wpt = room ? (Wt + WQN) : Wt;
    float* Ent = room ? (float*)(Wpt + WPN) : (float*)(Wt + WQN);

    prep_kernel<<<dim3(room ? 3072 : 2816), 256, 0, stream>>>(
        x, Wqkv, Wproj, xb, Wt, Wpt);
    gemm_db<128, 0><<<dim3(24, 32), 256, 0, stream>>>(
        xb, Wt, BQ * TQ, 3 * DIMQ, DIMQ, Qb, Kb, Vtb, nullptr, nullptr);
    if (!room)
        tr_cvt<<<dim3(16, 16), 256, 0, stream>>>(Wproj, Wpt, DIMQ, DIMQ);
    attn_kernel<<<dim3(16, BQ * HQ), 256, 0, stream>>>(Qb, Kb, Vtb, AO, Ent);
    gemm_db<64, 1><<<dim3(8, 64), 256, 0, stream>>>(
        AO, Wpt, BQ * TQ, DIMQ, DIMQ, nullptr, nullptr, nullptr, out, Ent);
}